// Round 1
// baseline (798.488 us; speedup 1.0000x reference)
//
#include <hip/hip_runtime.h>
#include <hip/hip_bf16.h>

#define NU 160000
#define NM 60000
#define DD 64
#define NE 5000000
#define NL 200000

// res = x + (1/2 + 1/3 + 1/4) * agg = x + (13/12)*agg  (all layers propagate layer-0)
#define COEF (13.0f / 12.0f)

#define SHIFT_U 9                               // 512 users/bucket (bucket id of virtual key too)
#define SHIFT_M 7                               // 128 movies/bucket
#define NBU ((NU + (1 << SHIFT_U) - 1) >> SHIFT_U)   // 313
#define NBM ((NM + (1 << SHIFT_M) - 1) >> SHIFT_M)   // 469
#define VB_U 16   // movie id fits 16 bits (60000 < 65536)
#define VB_M 18   // user id fits 18 bits (160000 < 262144)

// source blocking: movie sources split in 2 (y_m slice 3.84 MB), user sources in 6 (y_u slice 3.46 MB)
#define UDIV 30000        // movie block = movie / 30000  -> 0..1
#define LG_U 1            // virtual key factor 2
#define MDIV 27000        // user block = user / 27000    -> 0..5
#define LG_M 3            // virtual key factor 8 (6 active)
#define NPASS_U 2
#define NPASS_M 6
#define NVU (NU << LG_U)  // 320000 virtual destinations
#define NVM (NM << LG_M)  // 480000 virtual destinations
#define BS 1024           // virtual nodes per bucket (shift' = 10 on both sides)

// ---------------- pass A: bucket counts only ----------------

#define CEC 16   // edges/thread

__global__ void bucket_count_kernel(const int* __restrict__ ef, const int* __restrict__ et,
                                    int* __restrict__ gbh_u, int* __restrict__ gbh_m) {
    __shared__ int bhu[NBU], bhm[NBM];
    int tid = threadIdx.x;
    for (int i = tid; i < NBU; i += 256) bhu[i] = 0;
    for (int i = tid; i < NBM; i += 256) bhm[i] = 0;
    __syncthreads();
    int base = (blockIdx.x * 256 + tid) * CEC;
    if (base < NE) {   // NE % 16 == 0 -> all-or-none
        const int4* f4 = (const int4*)(ef + base);
        const int4* t4 = (const int4*)(et + base);
        #pragma unroll
        for (int q = 0; q < CEC / 4; q++) {
            int4 ff = f4[q]; int4 tt = t4[q];
            atomicAdd(&bhm[ff.x >> SHIFT_M], 1); atomicAdd(&bhu[tt.x >> SHIFT_U], 1);
            atomicAdd(&bhm[ff.y >> SHIFT_M], 1); atomicAdd(&bhu[tt.y >> SHIFT_U], 1);
            atomicAdd(&bhm[ff.z >> SHIFT_M], 1); atomicAdd(&bhu[tt.z >> SHIFT_U], 1);
            atomicAdd(&bhm[ff.w >> SHIFT_M], 1); atomicAdd(&bhu[tt.w >> SHIFT_U], 1);
        }
    }
    __syncthreads();
    for (int i = tid; i < NBU; i += 256) if (bhu[i]) atomicAdd(&gbh_u[i], bhu[i]);
    for (int i = tid; i < NBM; i += 256) if (bhm[i]) atomicAdd(&gbh_m[i], bhm[i]);
}

// ---------------- small exclusive scan (n <= 1024); out[n]=total; cursor copy ----------------

__global__ void scan_small_kernel(const int* __restrict__ in, int* __restrict__ out,
                                  int* __restrict__ cur, int n) {
    __shared__ int buf[256];
    int tid = threadIdx.x;
    int idx = tid * 4;
    int v0 = (idx + 0 < n) ? in[idx + 0] : 0;
    int v1 = (idx + 1 < n) ? in[idx + 1] : 0;
    int v2 = (idx + 2 < n) ? in[idx + 2] : 0;
    int v3 = (idx + 3 < n) ? in[idx + 3] : 0;
    int s = v0 + v1 + v2 + v3;
    buf[tid] = s;
    __syncthreads();
    for (int off = 1; off < 256; off <<= 1) {
        int t = (tid >= off) ? buf[tid - off] : 0;
        __syncthreads();
        buf[tid] += t;
        __syncthreads();
    }
    int p = buf[tid] - s;
    if (idx + 0 < n) { out[idx + 0] = p; if (cur) cur[idx + 0] = p; p += v0; }
    if (idx + 1 < n) { out[idx + 1] = p; if (cur) cur[idx + 1] = p; p += v1; }
    if (idx + 2 < n) { out[idx + 2] = p; if (cur) cur[idx + 2] = p; p += v2; }
    if (idx + 3 < n) { out[idx + 3] = p; if (cur) cur[idx + 3] = p; p += v3; }
    if (tid == 255) out[n] = buf[255];
}

// ---------------- coarse partition into bucket-grouped staging (packed int32) ----------------
// virtual key = (dest << lg) | src_block; bucket = keyv >> 10 (same bucket ids as before)

#define PEC 16   // edges/thread; 4096/block

__global__ void partition_kernel(const int* __restrict__ key, const int* __restrict__ val,
                                 int* __restrict__ bcur, int* __restrict__ stage,
                                 int nb, int valbits, int mode) {
    __shared__ int lh[512];
    __shared__ int lbase[512];
    int tid = threadIdx.x;
    for (int i = tid; i < nb; i += 256) lh[i] = 0;
    __syncthreads();
    int base = (blockIdx.x * 256 + tid) * PEC;
    int kv_[PEC], v_[PEC], br_[PEC];
    bool act = base < NE;   // NE % 16 == 0 -> all-or-none
    if (act) {
        int k_[PEC];
        const int4* k4 = (const int4*)(key + base);
        const int4* v4 = (const int4*)(val + base);
        #pragma unroll
        for (int q = 0; q < PEC / 4; q++) {
            int4 kk = k4[q]; int4 vv = v4[q];
            k_[q * 4 + 0] = kk.x; k_[q * 4 + 1] = kk.y; k_[q * 4 + 2] = kk.z; k_[q * 4 + 3] = kk.w;
            v_[q * 4 + 0] = vv.x; v_[q * 4 + 1] = vv.y; v_[q * 4 + 2] = vv.z; v_[q * 4 + 3] = vv.w;
        }
        #pragma unroll
        for (int q = 0; q < PEC; q++) {
            int kv;
            if (mode == 0) kv = (k_[q] << LG_U) | (v_[q] >= UDIV ? 1 : 0);
            else           kv = (k_[q] << LG_M) | (int)((unsigned)v_[q] / MDIV);
            kv_[q] = kv;
            int b = kv >> 10;
            int r = atomicAdd(&lh[b], 1);       // rank within (block,bucket) < 4096
            br_[q] = (b << 13) | r;
        }
    }
    __syncthreads();
    for (int i = tid; i < nb; i += 256) lbase[i] = lh[i] ? atomicAdd(&bcur[i], lh[i]) : 0;
    __syncthreads();
    if (act) {
        #pragma unroll
        for (int q = 0; q < PEC; q++) {
            int b = br_[q] >> 13;
            int r = br_[q] & 8191;
            stage[lbase[b] + r] = ((kv_[q] & (BS - 1)) << valbits) | v_[q];
        }
    }
}

// ---------------- per-bucket build: rp+pay over virtual nodes, all in LDS ----------------

__global__ void build_kernel(const int* __restrict__ stage, const int* __restrict__ bo,
                             int* __restrict__ rp, int* __restrict__ pay,
                             int n, int valbits) {
    __shared__ int cnt[BS];
    __shared__ int tmp[BS];
    int b = blockIdx.x;
    int tid = threadIdx.x;
    int base = b << 10;
    int nn = min(BS, n - base);
    int vmask = (1 << valbits) - 1;
    int s0 = bo[b];
    int s1 = bo[b + 1];

    for (int i = tid; i < BS; i += 256) cnt[i] = 0;
    __syncthreads();
    // pass 1: histogram over bucket-local virtual keys
    for (int e = s0 + tid; e < s1; e += 256)
        atomicAdd(&cnt[stage[e] >> valbits], 1);
    __syncthreads();
    int ov[4];
    #pragma unroll
    for (int q = 0; q < 4; q++) ov[q] = cnt[tid + q * 256];
    // inclusive scan (Hillis-Steele over 1024)
    for (int off = 1; off < BS; off <<= 1) {
        int t[4];
        #pragma unroll
        for (int q = 0; q < 4; q++) {
            int i = tid + q * 256;
            t[q] = (i >= off) ? cnt[i - off] : 0;
        }
        __syncthreads();
        #pragma unroll
        for (int q = 0; q < 4; q++) cnt[tid + q * 256] += t[q];
        __syncthreads();
    }
    #pragma unroll
    for (int q = 0; q < 4; q++) {
        int i = tid + q * 256;
        int excl = cnt[i] - ov[q];
        tmp[i] = s0 + excl;
        if (i < nn) rp[base + i] = s0 + excl;
    }
    if (b == 0 && tid == 0) rp[n] = NE;
    __syncthreads();
    // pass 2: place payloads via LDS cursors
    for (int e = s0 + tid; e < s1; e += 256) {
        int p = stage[e];
        int pos = atomicAdd(&tmp[p >> valbits], 1);
        pay[pos] = p & vmask;
    }
}

// ---------------- inv from CSR rowptr diffs: deg(n) = rp[(n+1)<<lg] - rp[n<<lg] ----------------

__global__ void inv_from_rp_kernel(const int* __restrict__ rp, float* __restrict__ inv,
                                   int n, int lg) {
    int i = blockIdx.x * blockDim.x + threadIdx.x;
    if (i < n) {
        int d = rp[(i + 1) << lg] - rp[i << lg];
        inv[i] = (d > 0) ? rsqrtf((float)d) : 0.0f;
    }
}

// ---------------- prescale: y = bf16(inv_src * x_src) ----------------

__global__ void prescale_kernel(const float* __restrict__ x, const float* __restrict__ inv,
                                __hip_bfloat16* __restrict__ y, int total) {
    int i = blockIdx.x * blockDim.x + threadIdx.x;
    if (i < total) {
        int node = i >> 6;
        y[i] = __float2bfloat16(inv[node] * x[i]);
    }
}

// ---------------- gather, one source-block per dispatch (bf16 prescaled source rows) ----------------

__global__ void gather_kernel(const int* __restrict__ rp, const int* __restrict__ pay,
                              const float* __restrict__ inv_dst,
                              const __hip_bfloat16* __restrict__ y_src,
                              const float* __restrict__ x_dst,
                              float* __restrict__ res, int n, int lg, int h, int first) {
    int tid = blockIdx.x * blockDim.x + threadIdx.x;
    int node = tid >> 6;
    int lane = threadIdx.x & 63;
    if (node >= n) return;
    int vk = (node << lg) | h;
    int start = rp[vk];
    int end   = rp[vk + 1];
    if (!first && start == end) return;   // nothing to add for this block
    float acc = 0.0f;
    for (int i = start; i < end; i += 64) {
        int cnt = min(end - i, 64);
        int nid = (lane < cnt) ? pay[i + lane] : 0;
        int j = 0;
        for (; j + 4 <= cnt; j += 4) {
            int f0 = __shfl(nid, j + 0, 64);
            int f1 = __shfl(nid, j + 1, 64);
            int f2 = __shfl(nid, j + 2, 64);
            int f3 = __shfl(nid, j + 3, 64);
            float a0 = __bfloat162float(y_src[f0 * DD + lane]);
            float a1 = __bfloat162float(y_src[f1 * DD + lane]);
            float a2 = __bfloat162float(y_src[f2 * DD + lane]);
            float a3 = __bfloat162float(y_src[f3 * DD + lane]);
            acc += a0 + a1 + a2 + a3;
        }
        for (; j < cnt; j++) {
            int f0 = __shfl(nid, j, 64);
            acc += __bfloat162float(y_src[f0 * DD + lane]);
        }
    }
    int o = node * DD + lane;
    float basev = first ? x_dst[o] : res[o];
    res[o] = basev + COEF * inv_dst[node] * acc;
}

// ---------------- score ----------------

__global__ void score_kernel(const int* __restrict__ lm, const int* __restrict__ lu,
                             const float* __restrict__ ru, const float* __restrict__ rm,
                             float* __restrict__ scores) {
    int tid = blockIdx.x * blockDim.x + threadIdx.x;
    int l = tid >> 6;
    int d = threadIdx.x & 63;
    if (l < NL) {
        int u = lu[l];
        int m = lm[l];
        float v = ru[u * DD + d] * rm[m * DD + d];
        #pragma unroll
        for (int off = 32; off >= 1; off >>= 1)
            v += __shfl_down(v, off, 64);
        if (d == 0) scores[l] = v;
    }
}

// ---------------- fallback: atomic agg path ----------------

__global__ void degree_kernel_f(const int* __restrict__ ef, const int* __restrict__ et,
                                float* __restrict__ deg_m, float* __restrict__ deg_u) {
    int i = blockIdx.x * blockDim.x + threadIdx.x;
    if (i < NE) {
        atomicAdd(&deg_m[ef[i]], 1.0f);
        atomicAdd(&deg_u[et[i]], 1.0f);
    }
}

__global__ void inv_kernel_f(float* __restrict__ deg, int n) {
    int i = blockIdx.x * blockDim.x + threadIdx.x;
    if (i < n) {
        float d = deg[i];
        deg[i] = (d > 0.0f) ? (1.0f / sqrtf(d)) : 0.0f;
    }
}

__global__ void agg_kernel_f(const int* __restrict__ ef, const int* __restrict__ et,
                             const float* __restrict__ inv_m, const float* __restrict__ inv_u,
                             const float* __restrict__ x_u, const float* __restrict__ x_m,
                             float* __restrict__ res_u, float* __restrict__ res_m) {
    int tid = blockIdx.x * blockDim.x + threadIdx.x;
    int e = tid >> 6;
    int d = tid & 63;
    if (e < NE) {
        int f = ef[e];
        int t = et[e];
        float norm = inv_m[f] * inv_u[t] * COEF;
        atomicAdd(&res_u[t * DD + d], norm * x_m[f * DD + d]);
        atomicAdd(&res_m[f * DD + d], norm * x_u[t * DD + d]);
    }
}

__global__ void add_base_kernel_f(const float* __restrict__ xu, const float* __restrict__ xm,
                                  float* __restrict__ ru, float* __restrict__ rm) {
    int i = blockIdx.x * blockDim.x + threadIdx.x;
    const int nu = NU * DD;
    const int nm = NM * DD;
    if (i < nu) {
        ru[i] += xu[i];
    } else if (i < nu + nm) {
        int j = i - nu;
        rm[j] += xm[j];
    }
}

// ---------------- launch ----------------

extern "C" void kernel_launch(void* const* d_in, const int* in_sizes, int n_in,
                              void* d_out, int out_size, void* d_ws, size_t ws_size,
                              hipStream_t stream) {
    const float* emb_user  = (const float*)d_in[0];
    const float* emb_movie = (const float*)d_in[1];
    const int* edge_from   = (const int*)d_in[4];
    const int* edge_to     = (const int*)d_in[5];
    const int* label_movie = (const int*)d_in[6];
    const int* label_user  = (const int*)d_in[7];

    float* out    = (float*)d_out;
    float* scores = out;                              // [NL]
    float* res_u  = out + NL;                         // [NU*DD]
    float* res_m  = out + NL + (size_t)NU * DD;       // [NM*DD]

    // ws layout
    int*   gbh_u  = (int*)d_ws;                       // NBU  (zeroed)
    int*   gbh_m  = gbh_u + NBU;                      // NBM  (zeroed)
    int*   bo_u   = gbh_m + NBM;                      // NBU+1
    int*   bcur_u = bo_u + NBU + 1;                   // NBU
    int*   bo_m   = bcur_u + NBU;                     // NBM+1
    int*   bcur_m = bo_m + NBM + 1;                   // NBM
    float* inv_u  = (float*)(bcur_m + NBM);           // NU
    float* inv_m  = inv_u + NU;                       // NM
    int*   rp_u   = (int*)(inv_m + NM);               // NVU+1
    int*   rp_m   = rp_u + NVU + 1;                   // NVM+1
    int*   pay_u  = rp_m + NVM + 1;                   // NE
    int*   pay_m  = pay_u + NE;                       // NE
    // union region: stage (NE ints, dead after builds) then y_u/y_m (bf16)
    int*   ureg   = pay_m + NE;
    int*   stage  = ureg;                             // NE ints
    __hip_bfloat16* y_u = (__hip_bfloat16*)ureg;                      // NU*DD bf16
    __hip_bfloat16* y_m = (__hip_bfloat16*)(ureg + (size_t)NU * DD / 2); // NM*DD bf16

    size_t ysz    = (size_t)(NU + NM) * DD / 2;       // ints for y region
    size_t uni    = (size_t)NE > ysz ? (size_t)NE : ysz;
    size_t needed = ((size_t)(ureg - (int*)d_ws) + uni) * sizeof(int);

    if (ws_size >= needed) {
        hipMemsetAsync(gbh_u, 0, (size_t)(NBU + NBM) * sizeof(int), stream);

        bucket_count_kernel<<<(NE / CEC + 255) / 256, 256, 0, stream>>>(
            edge_from, edge_to, gbh_u, gbh_m);
        scan_small_kernel<<<1, 256, 0, stream>>>(gbh_u, bo_u, bcur_u, NBU);
        scan_small_kernel<<<1, 256, 0, stream>>>(gbh_m, bo_m, bcur_m, NBM);

        // u-side: dest = user (edge_to), src = movie (edge_from), 2 source blocks
        partition_kernel<<<(NE / PEC + 255) / 256, 256, 0, stream>>>(
            edge_to, edge_from, bcur_u, stage, NBU, VB_U, 0);
        build_kernel<<<NBU, 256, 0, stream>>>(stage, bo_u, rp_u, pay_u, NVU, VB_U);

        // m-side: dest = movie (edge_from), src = user (edge_to), 6 source blocks
        partition_kernel<<<(NE / PEC + 255) / 256, 256, 0, stream>>>(
            edge_from, edge_to, bcur_m, stage, NBM, VB_M, 1);
        build_kernel<<<NBM, 256, 0, stream>>>(stage, bo_m, rp_m, pay_m, NVM, VB_M);

        // inv from total degree (rowptr diffs across the virtual-node group)
        inv_from_rp_kernel<<<(NU + 255) / 256, 256, 0, stream>>>(rp_u, inv_u, NU, LG_U);
        inv_from_rp_kernel<<<(NM + 255) / 256, 256, 0, stream>>>(rp_m, inv_m, NM, LG_M);

        // prescale (stage is dead now; y overlays it)
        prescale_kernel<<<((size_t)NU * DD + 255) / 256, 256, 0, stream>>>(
            emb_user, inv_u, y_u, NU * DD);
        prescale_kernel<<<((size_t)NM * DD + 255) / 256, 256, 0, stream>>>(
            emb_movie, inv_m, y_m, NM * DD);

        // blocked gathers: each pass's hot y-slice fits one XCD L2
        for (int h = 0; h < NPASS_U; h++)
            gather_kernel<<<((size_t)NU * 64 + 255) / 256, 256, 0, stream>>>(
                rp_u, pay_u, inv_u, y_m, emb_user, res_u, NU, LG_U, h, h == 0);
        for (int h = 0; h < NPASS_M; h++)
            gather_kernel<<<((size_t)NM * 64 + 255) / 256, 256, 0, stream>>>(
                rp_m, pay_m, inv_m, y_u, emb_movie, res_m, NM, LG_M, h, h == 0);
    } else {
        // ---- fallback: atomic path ----
        float* fdeg_u = (float*)d_ws;
        float* fdeg_m = fdeg_u + NU;
        hipMemsetAsync(res_u, 0, (size_t)(NU + NM) * DD * sizeof(float), stream);
        hipMemsetAsync(fdeg_u, 0, (size_t)(NU + NM) * sizeof(float), stream);
        degree_kernel_f<<<(NE + 255) / 256, 256, 0, stream>>>(edge_from, edge_to, fdeg_m, fdeg_u);
        inv_kernel_f<<<(NU + NM + 255) / 256, 256, 0, stream>>>(fdeg_u, NU + NM);
        agg_kernel_f<<<((size_t)NE * 64 + 255) / 256, 256, 0, stream>>>(
            edge_from, edge_to, fdeg_m, fdeg_u, emb_user, emb_movie, res_u, res_m);
        add_base_kernel_f<<<((NU + NM) * DD + 255) / 256, 256, 0, stream>>>(
            emb_user, emb_movie, res_u, res_m);
    }

    score_kernel<<<((size_t)NL * 64 + 255) / 256, 256, 0, stream>>>(
        label_movie, label_user, res_u, res_m, scores);
}